// Round 6
// baseline (343.122 us; speedup 1.0000x reference)
//
#include <hip/hip_runtime.h>
#include <math.h>

#define N_NODES 10000
#define E_EDGES 160000
#define E_TOT   170000   // E + self loops
#define MAXDEG  128
#define MPAD    10112    // 79 * 128

typedef _Float16 f16x8 __attribute__((ext_vector_type(8)));
typedef _Float16 f16x4 __attribute__((ext_vector_type(4)));
typedef float    f32x4 __attribute__((ext_vector_type(4)));

__device__ __forceinline__ float leaky(float e) { return (e > 0.f) ? e : 0.2f * e; }

// ---------------- graph CSR build (by dst) ----------------
__global__ void count_kernel(const int* __restrict__ ei, int* __restrict__ deg) {
    int e = blockIdx.x * 256 + threadIdx.x;
    if (e >= E_TOT) return;
    int dst = (e < E_EDGES) ? ei[E_EDGES + e] : (e - E_EDGES);
    atomicAdd(&deg[dst], 1);
}

__global__ void scan_kernel(const int* __restrict__ deg, int* __restrict__ rowptr,
                            int* __restrict__ cursor) {
    __shared__ int sums[1024];
    int t = threadIdx.x;
    const int CH = (N_NODES + 1023) / 1024;
    int base = t * CH;
    int s = 0;
    for (int j = 0; j < CH; j++) { int i = base + j; if (i < N_NODES) s += deg[i]; }
    sums[t] = s; __syncthreads();
    for (int off = 1; off < 1024; off <<= 1) {
        int v = (t >= off) ? sums[t - off] : 0;
        __syncthreads();
        sums[t] += v;
        __syncthreads();
    }
    int excl = (t == 0) ? 0 : sums[t - 1];
    for (int j = 0; j < CH; j++) {
        int i = base + j;
        if (i < N_NODES) { rowptr[i] = excl; cursor[i] = excl; excl += deg[i]; }
    }
    if (t == 1023) rowptr[N_NODES] = sums[1023];
}

__global__ void scatter_kernel(const int* __restrict__ ei, int* __restrict__ cursor,
                               int* __restrict__ perm_src) {
    int e = blockIdx.x * 256 + threadIdx.x;
    if (e >= E_TOT) return;
    int src, dst;
    if (e < E_EDGES) { src = ei[e]; dst = ei[E_EDGES + e]; }
    else { src = e - E_EDGES; dst = src; }
    int pos = atomicAdd(&cursor[dst], 1);
    perm_src[pos] = src;
}

// ---------------- all conversions / padding in one kernel ----------------
#define SEG0 (MPAD * 64)               // xh1
#define SEG1 (1024 * 64)               // W1h
#define SEG2 (1024 * 1024)             // W2h
#define SEG3 (768 * 1024)              // W3p (head-padded rows)
#define SEG4 768                        // asp/adp
#define SEG5 ((MPAD - N_NODES) * 1024) // xh zero tail
#define CVT_TOTAL (SEG0 + SEG1 + SEG2 + SEG3 + SEG4 + SEG5)

__global__ void cvt_all(const float* __restrict__ x, const float* __restrict__ W1,
                        const float* __restrict__ W2, const float* __restrict__ W3,
                        const float* __restrict__ as3, const float* __restrict__ ad3,
                        _Float16* __restrict__ xh1, _Float16* __restrict__ W1h,
                        _Float16* __restrict__ W2h, _Float16* __restrict__ W3p,
                        float* __restrict__ asp, float* __restrict__ adp,
                        _Float16* __restrict__ xh) {
    int i = blockIdx.x * 256 + threadIdx.x;
    if (i < SEG0) {
        int r = i >> 6, c = i & 63;
        xh1[i] = (r < N_NODES && c < 50) ? (_Float16)x[r * 50 + c] : (_Float16)0.f;
        return;
    }
    i -= SEG0;
    if (i < SEG1) {
        int r = i >> 6, c = i & 63;
        W1h[i] = (c < 50) ? (_Float16)W1[r * 50 + c] : (_Float16)0.f;
        return;
    }
    i -= SEG1;
    if (i < SEG2) { W2h[i] = (_Float16)W2[i]; return; }
    i -= SEG2;
    if (i < SEG3) {
        int r = i >> 10, k = i & 1023;
        int hh = r >> 7, cc = r & 127;
        W3p[i] = (cc < 121) ? (_Float16)W3[(size_t)(hh * 121 + cc) * 1024 + k] : (_Float16)0.f;
        return;
    }
    i -= SEG3;
    if (i < SEG4) {
        int hh = i >> 7, cc = i & 127;
        asp[i] = (cc < 121) ? as3[hh * 121 + cc] : 0.f;
        adp[i] = (cc < 121) ? ad3[hh * 121 + cc] : 0.f;
        return;
    }
    i -= SEG4;
    if (i < SEG5) xh[N_NODES * 1024 + i] = (_Float16)0.f;
}

// ---------------- fp16 MFMA GEMM + fused attention-logit epilogue ----------------
// C16[m,n] = sum_k A[m,k]*B[n,k]; also esrc[m,h] += sum_col C*a_s, edst likewise.
__device__ __forceinline__ void gload_lds(const _Float16* g, _Float16* l) {
    __builtin_amdgcn_global_load_lds(
        (const __attribute__((address_space(1))) void*)g,
        (__attribute__((address_space(3))) void*)l, 16, 0, 0);
}

template<int HSHIFT>   // head = col >> HSHIFT  (8 for layers 1-2; 7 for padded layer 3)
__global__ __launch_bounds__(256) void gemm_attn(const _Float16* __restrict__ A,
                                                 const _Float16* __restrict__ B,
                                                 _Float16* __restrict__ C,
                                                 const float* __restrict__ a_s,
                                                 const float* __restrict__ a_d,
                                                 float* __restrict__ esrc,
                                                 float* __restrict__ edst,
                                                 int M, int Nn, int Kp, int ldc, int H) {
    __shared__ _Float16 lds[16384];
    const int tid  = threadIdx.x;
    const int bm   = blockIdx.y * 128, bn = blockIdx.x * 128;
    const int w    = tid >> 6, lane = tid & 63;
    const int wr   = w >> 1,   wc   = w & 1;
    const int la   = lane & 15, g = lane >> 4;

    f32x4 acc[4][4] = {};

    const int srow = tid >> 3;
    const int skb0 = (tid & 7) * 16;

    for (int k0 = 0; k0 < Kp; k0 += 64) {
        __syncthreads();
#pragma unroll
        for (int i = 0; i < 4; i++) {
            int row = i * 32 + srow;
            int kb  = skb0 ^ ((row & 7) << 4);
            gload_lds(A + (size_t)(bm + row) * Kp + k0 + (kb >> 1),
                      lds + i * 2048 + w * 512);
        }
#pragma unroll
        for (int i = 0; i < 4; i++) {
            int row = i * 32 + srow;
            int kb  = skb0 ^ ((row & 7) << 4);
            gload_lds(B + (size_t)(bn + row) * Kp + k0 + (kb >> 1),
                      lds + 8192 + i * 2048 + w * 512);
        }
        asm volatile("s_waitcnt vmcnt(0)");
        __syncthreads();
#pragma unroll
        for (int s = 0; s < 2; s++) {
            f16x8 af[4], bf[4];
#pragma unroll
            for (int m = 0; m < 4; m++) {
                int r  = wr * 64 + m * 16 + la;
                int bc = (s * 64 + g * 16) ^ ((r & 7) << 4);
                af[m] = *(const f16x8*)(lds + r * 64 + (bc >> 1));
            }
#pragma unroll
            for (int n = 0; n < 4; n++) {
                int r  = wc * 64 + n * 16 + la;
                int bc = (s * 64 + g * 16) ^ ((r & 7) << 4);
                bf[n] = *(const f16x8*)(lds + 8192 + r * 64 + (bc >> 1));
            }
#pragma unroll
            for (int m = 0; m < 4; m++)
#pragma unroll
                for (int n = 0; n < 4; n++)
                    acc[m][n] = __builtin_amdgcn_mfma_f32_16x16x32_f16(af[m], bf[n], acc[m][n], 0, 0, 0);
        }
    }
    // C write (fp16)
#pragma unroll
    for (int m = 0; m < 4; m++) {
#pragma unroll
        for (int n = 0; n < 4; n++) {
            int col = bn + wc * 64 + n * 16 + la;
            if (col >= Nn) continue;
#pragma unroll
            for (int r = 0; r < 4; r++) {
                int row = bm + wr * 64 + m * 16 + g * 4 + r;
                if (row < M) C[(size_t)row * ldc + col] = (_Float16)acc[m][n][r];
            }
        }
    }
    // fused attention logits: wave covers cols [bn+wc*64, +64) -> one head
    {
        const int hh = (bn + wc * 64) >> HSHIFT;
        float as_n[4], ad_n[4];
#pragma unroll
        for (int n = 0; n < 4; n++) {
            int col = bn + wc * 64 + n * 16 + la;
            as_n[n] = a_s[col];
            ad_n[n] = a_d[col];
        }
#pragma unroll
        for (int m = 0; m < 4; m++) {
#pragma unroll
            for (int r = 0; r < 4; r++) {
                float s1 = acc[m][0][r] * as_n[0] + acc[m][1][r] * as_n[1]
                         + acc[m][2][r] * as_n[2] + acc[m][3][r] * as_n[3];
                float s2 = acc[m][0][r] * ad_n[0] + acc[m][1][r] * ad_n[1]
                         + acc[m][2][r] * ad_n[2] + acc[m][3][r] * ad_n[3];
#pragma unroll
                for (int off = 1; off < 16; off <<= 1) {
                    s1 += __shfl_xor(s1, off);
                    s2 += __shfl_xor(s2, off);
                }
                if (la == 0) {
                    int row = bm + wr * 64 + m * 16 + g * 4 + r;
                    if (row < M) {
                        atomicAdd(&esrc[(size_t)row * H + hh], s1);
                        atomicAdd(&edst[(size_t)row * H + hh], s2);
                    }
                }
            }
        }
    }
}

// ---------------- big-layer aggregate: 2 dsts/block, f16x8 gather, fused epilogue ----------------
template<int RES>
__global__ __launch_bounds__(256) void agg_big(const _Float16* __restrict__ h,
        const float* __restrict__ esrc, const float* __restrict__ edst,
        const int* __restrict__ rowptr, const int* __restrict__ perm_src,
        const float* __restrict__ bias, float* __restrict__ xbuf,
        _Float16* __restrict__ xh) {
    __shared__ int   srcs[2][MAXDEG];
    __shared__ float al[2][MAXDEG * 5];
    __shared__ float mh[2][4], sh[2][4];
    __shared__ int   degs[2];
    const int tid = threadIdx.x;
    const int sub = tid >> 7, stid = tid & 127;
    const int lane = tid & 63, w = tid >> 6, wsub = w >> 1;
    const int d = blockIdx.x * 2 + sub;
    const int r0 = rowptr[d];
    int deg = rowptr[d + 1] - r0;
    if (deg > MAXDEG) deg = MAXDEG;
    if (stid == 0) degs[sub] = deg;

    float ev[4];
    if (stid < deg) {
        int s = perm_src[r0 + stid];
        srcs[sub][stid] = s;
        float4 es = *(const float4*)(esrc + (size_t)s * 4);
        float4 ed = *(const float4*)(edst + (size_t)d * 4);
        ev[0] = leaky(es.x + ed.x);
        ev[1] = leaky(es.y + ed.y);
        ev[2] = leaky(es.z + ed.z);
        ev[3] = leaky(es.w + ed.w);
#pragma unroll
        for (int j = 0; j < 4; j++) al[sub][stid * 5 + j] = ev[j];
    }
    __syncthreads();
    {   // wave w reduces heads {2*(w&1), 2*(w&1)+1} of dst wsub
        int degw = degs[wsub];
#pragma unroll
        for (int jj = 0; jj < 2; jj++) {
            int hh = (w & 1) * 2 + jj;
            float v0 = (lane < degw)      ? al[wsub][lane * 5 + hh]        : -1e30f;
            float v1 = (lane + 64 < degw) ? al[wsub][(lane + 64) * 5 + hh] : -1e30f;
            float m = fmaxf(v0, v1);
#pragma unroll
            for (int off = 32; off; off >>= 1) m = fmaxf(m, __shfl_xor(m, off));
            float s = ((lane < degw) ? __expf(v0 - m) : 0.f)
                    + ((lane + 64 < degw) ? __expf(v1 - m) : 0.f);
#pragma unroll
            for (int off = 32; off; off >>= 1) s += __shfl_xor(s, off);
            if (lane == 0) { mh[wsub][hh] = m; sh[wsub][hh] = 1.f / fmaxf(s, 1e-16f); }
        }
    }
    __syncthreads();
    if (stid < deg) {
#pragma unroll
        for (int j = 0; j < 4; j++) al[sub][stid * 5 + j] = __expf(ev[j] - mh[sub][j]) * sh[sub][j];
    }
    __syncthreads();

    // gather: 128 threads x f16x8 = 1024 cols per dst
    const int c0 = stid * 8, hh = stid >> 5;
    float acc[8] = {};
    const float* myal = al[sub];
    const int* mysrc = srcs[sub];
#pragma unroll 4
    for (int t = 0; t < deg; t++) {
        float a = myal[t * 5 + hh];
        f16x8 v = *(const f16x8*)(h + (size_t)mysrc[t] * 1024 + c0);
#pragma unroll
        for (int j = 0; j < 8; j++) acc[j] += a * (float)v[j];
    }
    size_t o = (size_t)d * 1024 + c0;
    f16x8 hv;
#pragma unroll
    for (int q = 0; q < 2; q++) {
        float4 bv = *(const float4*)(bias + c0 + q * 4);
        float4 r = RES ? *(const float4*)(xbuf + o + q * 4) : make_float4(0.f, 0.f, 0.f, 0.f);
        float v0 = acc[q * 4 + 0] + bv.x + r.x;
        float v1 = acc[q * 4 + 1] + bv.y + r.y;
        float v2 = acc[q * 4 + 2] + bv.z + r.z;
        float v3 = acc[q * 4 + 3] + bv.w + r.w;
        v0 = (v0 > 0.f) ? v0 : expm1f(v0);
        v1 = (v1 > 0.f) ? v1 : expm1f(v1);
        v2 = (v2 > 0.f) ? v2 : expm1f(v2);
        v3 = (v3 > 0.f) ? v3 : expm1f(v3);
        *(float4*)(xbuf + o + q * 4) = make_float4(v0, v1, v2, v3);
        hv[q * 4 + 0] = (_Float16)v0; hv[q * 4 + 1] = (_Float16)v1;
        hv[q * 4 + 2] = (_Float16)v2; hv[q * 4 + 3] = (_Float16)v3;
    }
    *(f16x8*)(xh + o) = hv;
}

// ---------------- layer-3 aggregate: 2 dsts/block, f16x8 gather, mean+sigmoid ----------------
__global__ __launch_bounds__(256) void agg_final(const _Float16* __restrict__ h,  // ld 768
        const float* __restrict__ esrc, const float* __restrict__ edst,
        const int* __restrict__ rowptr, const int* __restrict__ perm_src,
        const float* __restrict__ b3, float* __restrict__ out) {
    __shared__ int   srcs[2][MAXDEG];
    __shared__ float al[2][MAXDEG * 7];
    __shared__ float mh[2][6], sh[2][6];
    __shared__ float sO[2][768];
    __shared__ int   degs[2];
    const int tid = threadIdx.x;
    const int sub = tid >> 7, stid = tid & 127;
    const int lane = tid & 63, w = tid >> 6, wsub = w >> 1;
    const int d = blockIdx.x * 2 + sub;
    const int r0 = rowptr[d];
    int deg = rowptr[d + 1] - r0;
    if (deg > MAXDEG) deg = MAXDEG;
    if (stid == 0) degs[sub] = deg;

    float ev[6];
    if (stid < deg) {
        int s = perm_src[r0 + stid];
        srcs[sub][stid] = s;
        const float* pe = esrc + (size_t)s * 6;
        const float* pd = edst + (size_t)d * 6;
        float2 e0 = *(const float2*)(pe);
        float2 e1 = *(const float2*)(pe + 2);
        float2 e2 = *(const float2*)(pe + 4);
        float2 d0 = *(const float2*)(pd);
        float2 d1 = *(const float2*)(pd + 2);
        float2 d2 = *(const float2*)(pd + 4);
        ev[0] = leaky(e0.x + d0.x); ev[1] = leaky(e0.y + d0.y);
        ev[2] = leaky(e1.x + d1.x); ev[3] = leaky(e1.y + d1.y);
        ev[4] = leaky(e2.x + d2.x); ev[5] = leaky(e2.y + d2.y);
#pragma unroll
        for (int j = 0; j < 6; j++) al[sub][stid * 7 + j] = ev[j];
    }
    __syncthreads();
    {   // wave w reduces heads {3*(w&1)..+2} of dst wsub
        int degw = degs[wsub];
#pragma unroll
        for (int jj = 0; jj < 3; jj++) {
            int hh = (w & 1) * 3 + jj;
            float v0 = (lane < degw)      ? al[wsub][lane * 7 + hh]        : -1e30f;
            float v1 = (lane + 64 < degw) ? al[wsub][(lane + 64) * 7 + hh] : -1e30f;
            float m = fmaxf(v0, v1);
#pragma unroll
            for (int off = 32; off; off >>= 1) m = fmaxf(m, __shfl_xor(m, off));
            float s = ((lane < degw) ? __expf(v0 - m) : 0.f)
                    + ((lane + 64 < degw) ? __expf(v1 - m) : 0.f);
#pragma unroll
            for (int off = 32; off; off >>= 1) s += __shfl_xor(s, off);
            if (lane == 0) { mh[wsub][hh] = m; sh[wsub][hh] = 1.f / fmaxf(s, 1e-16f); }
        }
    }
    __syncthreads();
    if (stid < deg) {
#pragma unroll
        for (int j = 0; j < 6; j++) al[sub][stid * 7 + j] = __expf(ev[j] - mh[sub][j]) * sh[sub][j];
    }
    __syncthreads();

    // gather: 96 threads x f16x8 = 768 padded cols per dst
    if (stid < 96) {
        const int c0 = stid * 8, hh = stid >> 4;
        float acc[8] = {};
        const float* myal = al[sub];
        const int* mysrc = srcs[sub];
#pragma unroll 4
        for (int t = 0; t < deg; t++) {
            float a = myal[t * 7 + hh];
            f16x8 v = *(const f16x8*)(h + (size_t)mysrc[t] * 768 + c0);
#pragma unroll
            for (int j = 0; j < 8; j++) acc[j] += a * (float)v[j];
        }
        *(f32x4*)(sO[sub] + c0)     = *(f32x4*)(acc);
        *(f32x4*)(sO[sub] + c0 + 4) = *(f32x4*)(acc + 4);
    }
    __syncthreads();
    if (stid < 121) {
        float s = 0.f;
#pragma unroll
        for (int hh = 0; hh < 6; hh++) s += sO[sub][hh * 128 + stid];
        s = s * (1.f / 6.f) + b3[stid];
        out[(size_t)d * 121 + stid] = 1.f / (1.f + __expf(-s));
    }
}

// ---------------- launcher ----------------
extern "C" void kernel_launch(void* const* d_in, const int* in_sizes, int n_in,
                              void* d_out, int out_size, void* d_ws, size_t ws_size,
                              hipStream_t stream) {
    const float* x   = (const float*)d_in[0];
    const int*   ei  = (const int*)d_in[1];
    const float* W1  = (const float*)d_in[2];
    const float* as1 = (const float*)d_in[3];
    const float* ad1 = (const float*)d_in[4];
    const float* b1  = (const float*)d_in[5];
    const float* W2  = (const float*)d_in[6];
    const float* as2 = (const float*)d_in[7];
    const float* ad2 = (const float*)d_in[8];
    const float* b2  = (const float*)d_in[9];
    const float* W3  = (const float*)d_in[10];
    const float* as3 = (const float*)d_in[11];
    const float* ad3 = (const float*)d_in[12];
    const float* b3  = (const float*)d_in[13];
    float* out = (float*)d_out;

    float* fws  = (float*)d_ws;
    float* xbuf = fws;                      // N*1024 f32
    float* esrc = fws + 10240000;           // N*6
    float* edst = fws + 10300000;           // N*6 (contiguous after esrc)
    float* asp  = fws + 10360000;           // 768
    float* adp  = fws + 10360768;           // 768
    int*   iws  = (int*)(fws + 10361536);
    int* deg    = iws;                      // N
    int* rowptr = iws + N_NODES;            // N+1
    int* cursor = iws + 2 * N_NODES + 1;    // N
    int* perm   = iws + 3 * N_NODES + 1;    // E_TOT
    _Float16* f16b = (_Float16*)(fws + 10561544);
    _Float16* xh  = f16b;                          // MPAD*1024
    _Float16* xh1 = xh + (size_t)MPAD * 1024;      // MPAD*64
    _Float16* W1h = xh1 + (size_t)MPAD * 64;       // 1024*64
    _Float16* W2h = W1h + 1024 * 64;               // 1024*1024
    _Float16* W3p = W2h + 1024 * 1024;             // 768*1024 (head-padded)
    _Float16* h16 = W3p + 768 * 1024;              // N*1024

    hipMemsetAsync(deg, 0, N_NODES * sizeof(int), stream);
    count_kernel<<<(E_TOT + 255) / 256, 256, 0, stream>>>(ei, deg);
    scan_kernel<<<1, 1024, 0, stream>>>(deg, rowptr, cursor);
    scatter_kernel<<<(E_TOT + 255) / 256, 256, 0, stream>>>(ei, cursor, perm);

    dim3 blk(256);
    cvt_all<<<(CVT_TOTAL + 255) / 256, blk, 0, stream>>>(x, W1, W2, W3, as3, ad3,
                                                          xh1, W1h, W2h, W3p, asp, adp, xh);

    // ---- layer 1: K=50->64, H=4, C=256 ----
    {
        hipMemsetAsync(esrc, 0, 120000 * sizeof(float), stream);
        dim3 g(8, 79);
        gemm_attn<8><<<g, blk, 0, stream>>>(xh1, W1h, h16, as1, ad1, esrc, edst,
                                            N_NODES, 1024, 64, 1024, 4);
        agg_big<0><<<N_NODES / 2, blk, 0, stream>>>(h16, esrc, edst, rowptr, perm, b1, xbuf, xh);
    }
    // ---- layer 2: K=1024, H=4, C=256, residual ----
    {
        hipMemsetAsync(esrc, 0, 120000 * sizeof(float), stream);
        dim3 g(8, 79);
        gemm_attn<8><<<g, blk, 0, stream>>>(xh, W2h, h16, as2, ad2, esrc, edst,
                                            N_NODES, 1024, 1024, 1024, 4);
        agg_big<1><<<N_NODES / 2, blk, 0, stream>>>(h16, esrc, edst, rowptr, perm, b2, xbuf, xh);
    }
    // ---- layer 3: K=1024, H=6, C=121 (padded 128), mean heads + sigmoid ----
    {
        hipMemsetAsync(esrc, 0, 120000 * sizeof(float), stream);
        dim3 g(6, 79);
        gemm_attn<7><<<g, blk, 0, stream>>>(xh, W3p, h16, asp, adp, esrc, edst,
                                            N_NODES, 768, 1024, 768, 6);
        agg_final<<<N_NODES / 2, blk, 0, stream>>>(h16, esrc, edst, rowptr, perm, b3, out);
    }
}

// Round 7
// 298.156 us; speedup vs baseline: 1.1508x; 1.1508x over previous
//
#include <hip/hip_runtime.h>
#include <math.h>

#define N_NODES 10000
#define E_EDGES 160000
#define E_TOT   170000   // E + self loops
#define MAXDEG  128
#define MPAD    10112    // 79 * 128

typedef _Float16 f16x8 __attribute__((ext_vector_type(8)));
typedef _Float16 f16x4 __attribute__((ext_vector_type(4)));
typedef float    f32x4 __attribute__((ext_vector_type(4)));

__device__ __forceinline__ float leaky(float e) { return (e > 0.f) ? e : 0.2f * e; }

// ---------------- graph CSR build (by dst) ----------------
__global__ void count_kernel(const int* __restrict__ ei, int* __restrict__ deg) {
    int e = blockIdx.x * 256 + threadIdx.x;
    if (e >= E_TOT) return;
    int dst = (e < E_EDGES) ? ei[E_EDGES + e] : (e - E_EDGES);
    atomicAdd(&deg[dst], 1);
}

__global__ void scan_kernel(const int* __restrict__ deg, int* __restrict__ rowptr,
                            int* __restrict__ cursor) {
    __shared__ int sums[1024];
    int t = threadIdx.x;
    const int CH = (N_NODES + 1023) / 1024;
    int base = t * CH;
    int s = 0;
    for (int j = 0; j < CH; j++) { int i = base + j; if (i < N_NODES) s += deg[i]; }
    sums[t] = s; __syncthreads();
    for (int off = 1; off < 1024; off <<= 1) {
        int v = (t >= off) ? sums[t - off] : 0;
        __syncthreads();
        sums[t] += v;
        __syncthreads();
    }
    int excl = (t == 0) ? 0 : sums[t - 1];
    for (int j = 0; j < CH; j++) {
        int i = base + j;
        if (i < N_NODES) { rowptr[i] = excl; cursor[i] = excl; excl += deg[i]; }
    }
    if (t == 1023) rowptr[N_NODES] = sums[1023];
}

__global__ void scatter_kernel(const int* __restrict__ ei, int* __restrict__ cursor,
                               int* __restrict__ perm_src) {
    int e = blockIdx.x * 256 + threadIdx.x;
    if (e >= E_TOT) return;
    int src, dst;
    if (e < E_EDGES) { src = ei[e]; dst = ei[E_EDGES + e]; }
    else { src = e - E_EDGES; dst = src; }
    int pos = atomicAdd(&cursor[dst], 1);
    perm_src[pos] = src;
}

// ---------------- all conversions / padding in one kernel ----------------
#define SEG0 (MPAD * 64)               // xh1
#define SEG1 (1024 * 64)               // W1h
#define SEG2 (1024 * 1024)             // W2h
#define SEG3 (768 * 1024)              // W3p (head-padded rows)
#define SEG4 768                        // asp/adp
#define SEG5 ((MPAD - N_NODES) * 1024) // xh zero tail
#define CVT_TOTAL (SEG0 + SEG1 + SEG2 + SEG3 + SEG4 + SEG5)

__global__ void cvt_all(const float* __restrict__ x, const float* __restrict__ W1,
                        const float* __restrict__ W2, const float* __restrict__ W3,
                        const float* __restrict__ as3, const float* __restrict__ ad3,
                        _Float16* __restrict__ xh1, _Float16* __restrict__ W1h,
                        _Float16* __restrict__ W2h, _Float16* __restrict__ W3p,
                        float* __restrict__ asp, float* __restrict__ adp,
                        _Float16* __restrict__ xh) {
    int i = blockIdx.x * 256 + threadIdx.x;
    if (i < SEG0) {
        int r = i >> 6, c = i & 63;
        xh1[i] = (r < N_NODES && c < 50) ? (_Float16)x[r * 50 + c] : (_Float16)0.f;
        return;
    }
    i -= SEG0;
    if (i < SEG1) {
        int r = i >> 6, c = i & 63;
        W1h[i] = (c < 50) ? (_Float16)W1[r * 50 + c] : (_Float16)0.f;
        return;
    }
    i -= SEG1;
    if (i < SEG2) { W2h[i] = (_Float16)W2[i]; return; }
    i -= SEG2;
    if (i < SEG3) {
        int r = i >> 10, k = i & 1023;
        int hh = r >> 7, cc = r & 127;
        W3p[i] = (cc < 121) ? (_Float16)W3[(size_t)(hh * 121 + cc) * 1024 + k] : (_Float16)0.f;
        return;
    }
    i -= SEG3;
    if (i < SEG4) {
        int hh = i >> 7, cc = i & 127;
        asp[i] = (cc < 121) ? as3[hh * 121 + cc] : 0.f;
        adp[i] = (cc < 121) ? ad3[hh * 121 + cc] : 0.f;
        return;
    }
    i -= SEG4;
    if (i < SEG5) xh[N_NODES * 1024 + i] = (_Float16)0.f;
}

// ---------------- fp16 MFMA GEMM: C16[m,n] = sum_k A[m,k]*B[n,k] (fp16 out) ----------------
__device__ __forceinline__ void gload_lds(const _Float16* g, _Float16* l) {
    __builtin_amdgcn_global_load_lds(
        (const __attribute__((address_space(1))) void*)g,
        (__attribute__((address_space(3))) void*)l, 16, 0, 0);
}

__global__ __launch_bounds__(256) void gemm_mfma(const _Float16* __restrict__ A,
                                                 const _Float16* __restrict__ B,
                                                 _Float16* __restrict__ C,
                                                 int M, int Nn, int Kp, int ldc) {
    __shared__ _Float16 lds[16384];
    const int tid  = threadIdx.x;
    const int bm   = blockIdx.y * 128, bn = blockIdx.x * 128;
    const int w    = tid >> 6, lane = tid & 63;
    const int wr   = w >> 1,   wc   = w & 1;
    const int la   = lane & 15, g = lane >> 4;

    f32x4 acc[4][4] = {};

    const int srow = tid >> 3;
    const int skb0 = (tid & 7) * 16;

    for (int k0 = 0; k0 < Kp; k0 += 64) {
        __syncthreads();
#pragma unroll
        for (int i = 0; i < 4; i++) {
            int row = i * 32 + srow;
            int kb  = skb0 ^ ((row & 7) << 4);
            gload_lds(A + (size_t)(bm + row) * Kp + k0 + (kb >> 1),
                      lds + i * 2048 + w * 512);
        }
#pragma unroll
        for (int i = 0; i < 4; i++) {
            int row = i * 32 + srow;
            int kb  = skb0 ^ ((row & 7) << 4);
            gload_lds(B + (size_t)(bn + row) * Kp + k0 + (kb >> 1),
                      lds + 8192 + i * 2048 + w * 512);
        }
        asm volatile("s_waitcnt vmcnt(0)");
        __syncthreads();
#pragma unroll
        for (int s = 0; s < 2; s++) {
            f16x8 af[4], bf[4];
#pragma unroll
            for (int m = 0; m < 4; m++) {
                int r  = wr * 64 + m * 16 + la;
                int bc = (s * 64 + g * 16) ^ ((r & 7) << 4);
                af[m] = *(const f16x8*)(lds + r * 64 + (bc >> 1));
            }
#pragma unroll
            for (int n = 0; n < 4; n++) {
                int r  = wc * 64 + n * 16 + la;
                int bc = (s * 64 + g * 16) ^ ((r & 7) << 4);
                bf[n] = *(const f16x8*)(lds + 8192 + r * 64 + (bc >> 1));
            }
#pragma unroll
            for (int m = 0; m < 4; m++)
#pragma unroll
                for (int n = 0; n < 4; n++)
                    acc[m][n] = __builtin_amdgcn_mfma_f32_16x16x32_f16(af[m], bf[n], acc[m][n], 0, 0, 0);
        }
    }
#pragma unroll
    for (int m = 0; m < 4; m++) {
#pragma unroll
        for (int n = 0; n < 4; n++) {
            int col = bn + wc * 64 + n * 16 + la;
            if (col >= Nn) continue;
#pragma unroll
            for (int r = 0; r < 4; r++) {
                int row = bm + wr * 64 + m * 16 + g * 4 + r;
                if (row < M) C[(size_t)row * ldc + col] = (_Float16)acc[m][n][r];
            }
        }
    }
}

// ---------------- attn for H=4, HC=1024: one wave per node ----------------
__global__ __launch_bounds__(256) void attn4(const _Float16* __restrict__ h,
        const float* __restrict__ a_s, const float* __restrict__ a_d,
        float* __restrict__ esrc, float* __restrict__ edst) {
    const int w = threadIdx.x >> 6, lane = threadIdx.x & 63;
    const int node = blockIdx.x * 4 + w;
    const _Float16* row = h + (size_t)node * 1024;
    float ps[4], pd[4];
#pragma unroll
    for (int j = 0; j < 4; j++) {
        int c0 = j * 256 + lane * 4;
        f16x4 v = *(const f16x4*)(row + c0);
        float4 sa = *(const float4*)(a_s + c0);
        float4 da = *(const float4*)(a_d + c0);
        ps[j] = (float)v[0] * sa.x + (float)v[1] * sa.y + (float)v[2] * sa.z + (float)v[3] * sa.w;
        pd[j] = (float)v[0] * da.x + (float)v[1] * da.y + (float)v[2] * da.z + (float)v[3] * da.w;
    }
#pragma unroll
    for (int j = 0; j < 4; j++) {
#pragma unroll
        for (int off = 32; off; off >>= 1) {
            ps[j] += __shfl_xor(ps[j], off);
            pd[j] += __shfl_xor(pd[j], off);
        }
    }
    if (lane == 0) {
        *(float4*)(esrc + (size_t)node * 4) = make_float4(ps[0], ps[1], ps[2], ps[3]);
        *(float4*)(edst + (size_t)node * 4) = make_float4(pd[0], pd[1], pd[2], pd[3]);
    }
}

// ---------------- attn for layer 3 (padded head stride 128): one wave per node ----------------
__global__ __launch_bounds__(256) void attn6(const _Float16* __restrict__ h,
        const float* __restrict__ asp, const float* __restrict__ adp,
        float* __restrict__ esrc, float* __restrict__ edst) {
    const int w = threadIdx.x >> 6, lane = threadIdx.x & 63;
    const int node = blockIdx.x * 4 + w;
    const _Float16* row = h + (size_t)node * 768;
    float ps[3], pd[3];
#pragma unroll
    for (int j = 0; j < 3; j++) {
        int c0 = j * 256 + lane * 4;   // head = 2j + (lane>=32)
        f16x4 v = *(const f16x4*)(row + c0);
        float4 sa = *(const float4*)(asp + c0);
        float4 da = *(const float4*)(adp + c0);
        ps[j] = (float)v[0] * sa.x + (float)v[1] * sa.y + (float)v[2] * sa.z + (float)v[3] * sa.w;
        pd[j] = (float)v[0] * da.x + (float)v[1] * da.y + (float)v[2] * da.z + (float)v[3] * da.w;
    }
#pragma unroll
    for (int j = 0; j < 3; j++) {
#pragma unroll
        for (int off = 16; off; off >>= 1) {   // reduce within 32-lane halves
            ps[j] += __shfl_xor(ps[j], off);
            pd[j] += __shfl_xor(pd[j], off);
        }
    }
    if (lane == 0 || lane == 32) {
        int hb = lane >> 5;                    // 0: heads 0,2,4 ; 1: heads 1,3,5
        float* es = esrc + (size_t)node * 6;
        float* ed = edst + (size_t)node * 6;
#pragma unroll
        for (int j = 0; j < 3; j++) { es[2 * j + hb] = ps[j]; ed[2 * j + hb] = pd[j]; }
    }
}

// ---------------- big-layer aggregate: block per dst, parallel softmax, f16x4 gather ----------------
// Residual (RES=1) read from fp16 xh; output written to fp16 xh only (no f32 buffer).
template<int RES>
__global__ __launch_bounds__(256) void agg_big(const _Float16* __restrict__ h,
        const float* __restrict__ esrc, const float* __restrict__ edst,
        const int* __restrict__ rowptr, const int* __restrict__ perm_src,
        const float* __restrict__ bias, _Float16* __restrict__ xh) {
    __shared__ int   srcs[MAXDEG];
    __shared__ float al[MAXDEG * 5];      // stride 5: conflict-free strided access
    __shared__ float mh[4], sh[4];
    const int tid = threadIdx.x, lane = tid & 63, w = tid >> 6;
    const int d = blockIdx.x;
    const int r0 = rowptr[d];
    int deg = rowptr[d + 1] - r0;
    if (deg > MAXDEG) deg = MAXDEG;

    float ev[4];
    if (tid < deg) {
        int s = perm_src[r0 + tid];
        srcs[tid] = s;
        float4 es = *(const float4*)(esrc + (size_t)s * 4);
        float4 ed = *(const float4*)(edst + (size_t)d * 4);
        ev[0] = leaky(es.x + ed.x);
        ev[1] = leaky(es.y + ed.y);
        ev[2] = leaky(es.z + ed.z);
        ev[3] = leaky(es.w + ed.w);
#pragma unroll
        for (int j = 0; j < 4; j++) al[tid * 5 + j] = ev[j];
    }
    __syncthreads();
    {   // wave w reduces head w
        float v0 = (lane < deg)      ? al[lane * 5 + w]        : -1e30f;
        float v1 = (lane + 64 < deg) ? al[(lane + 64) * 5 + w] : -1e30f;
        float m = fmaxf(v0, v1);
#pragma unroll
        for (int off = 32; off; off >>= 1) m = fmaxf(m, __shfl_xor(m, off));
        float s = ((lane < deg) ? __expf(v0 - m) : 0.f)
                + ((lane + 64 < deg) ? __expf(v1 - m) : 0.f);
#pragma unroll
        for (int off = 32; off; off >>= 1) s += __shfl_xor(s, off);
        if (lane == 0) { mh[w] = m; sh[w] = 1.f / fmaxf(s, 1e-16f); }
    }
    __syncthreads();
    if (tid < deg) {
#pragma unroll
        for (int j = 0; j < 4; j++) al[tid * 5 + j] = __expf(ev[j] - mh[j]) * sh[j];
    }
    __syncthreads();

    // gather: 256 threads x f16x4 = 1024 cols
    const int c0 = tid * 4, hh = tid >> 6;
    f32x4 acc = {};
#pragma unroll 4
    for (int t = 0; t < deg; t++) {
        float a = al[t * 5 + hh];                       // broadcast within wave
        f16x4 v = *(const f16x4*)(h + (size_t)srcs[t] * 1024 + c0);
        acc[0] += a * (float)v[0]; acc[1] += a * (float)v[1];
        acc[2] += a * (float)v[2]; acc[3] += a * (float)v[3];
    }
    size_t o = (size_t)d * 1024 + c0;
    float4 bv = *(const float4*)(bias + c0);
    float r0v = 0.f, r1v = 0.f, r2v = 0.f, r3v = 0.f;
    if (RES) {
        f16x4 rv = *(const f16x4*)(xh + o);
        r0v = (float)rv[0]; r1v = (float)rv[1]; r2v = (float)rv[2]; r3v = (float)rv[3];
    }
    float v0 = acc[0] + bv.x + r0v;
    float v1 = acc[1] + bv.y + r1v;
    float v2 = acc[2] + bv.z + r2v;
    float v3 = acc[3] + bv.w + r3v;
    v0 = (v0 > 0.f) ? v0 : expm1f(v0);
    v1 = (v1 > 0.f) ? v1 : expm1f(v1);
    v2 = (v2 > 0.f) ? v2 : expm1f(v2);
    v3 = (v3 > 0.f) ? v3 : expm1f(v3);
    f16x4 hv; hv[0] = (_Float16)v0; hv[1] = (_Float16)v1; hv[2] = (_Float16)v2; hv[3] = (_Float16)v3;
    *(f16x4*)(xh + o) = hv;
}

// ---------------- layer-3 aggregate: block per dst, padded gather, mean+sigmoid ----------------
__global__ __launch_bounds__(256) void agg_final(const _Float16* __restrict__ h,  // ld 768, head stride 128
        const float* __restrict__ esrc, const float* __restrict__ edst,
        const int* __restrict__ rowptr, const int* __restrict__ perm_src,
        const float* __restrict__ b3, float* __restrict__ out) {
    __shared__ int   srcs[MAXDEG];
    __shared__ float al[MAXDEG * 7];      // stride 7: conflict-free strided access
    __shared__ float mh[6], sh[6];
    __shared__ float sO[768];
    const int tid = threadIdx.x, lane = tid & 63, w = tid >> 6;
    const int d = blockIdx.x;
    const int r0 = rowptr[d];
    int deg = rowptr[d + 1] - r0;
    if (deg > MAXDEG) deg = MAXDEG;

    float ev[6];
    if (tid < deg) {
        int s = perm_src[r0 + tid];
        srcs[tid] = s;
        const float* pe = esrc + (size_t)s * 6;
        const float* pd = edst + (size_t)d * 6;
#pragma unroll
        for (int j = 0; j < 6; j++) ev[j] = leaky(pe[j] + pd[j]);
#pragma unroll
        for (int j = 0; j < 6; j++) al[tid * 7 + j] = ev[j];
    }
    __syncthreads();
    for (int hh = w; hh < 6; hh += 4) {   // waves 0..3 -> heads 0..3, waves 0,1 -> 4,5
        float v0 = (lane < deg)      ? al[lane * 7 + hh]        : -1e30f;
        float v1 = (lane + 64 < deg) ? al[(lane + 64) * 7 + hh] : -1e30f;
        float m = fmaxf(v0, v1);
#pragma unroll
        for (int off = 32; off; off >>= 1) m = fmaxf(m, __shfl_xor(m, off));
        float s = ((lane < deg) ? __expf(v0 - m) : 0.f)
                + ((lane + 64 < deg) ? __expf(v1 - m) : 0.f);
#pragma unroll
        for (int off = 32; off; off >>= 1) s += __shfl_xor(s, off);
        if (lane == 0) { mh[hh] = m; sh[hh] = 1.f / fmaxf(s, 1e-16f); }
    }
    __syncthreads();
    if (tid < deg) {
#pragma unroll
        for (int j = 0; j < 6; j++) al[tid * 7 + j] = __expf(ev[j] - mh[j]) * sh[j];
    }
    __syncthreads();

    // gather: threads 0..191, f16x4 chunks over 768 padded cols
    if (tid < 192) {
        const int c0 = tid * 4, hh = tid >> 5;
        f32x4 acc = {};
#pragma unroll 4
        for (int t = 0; t < deg; t++) {
            float a = al[t * 7 + hh];
            f16x4 v = *(const f16x4*)(h + (size_t)srcs[t] * 768 + c0);
            acc[0] += a * (float)v[0]; acc[1] += a * (float)v[1];
            acc[2] += a * (float)v[2]; acc[3] += a * (float)v[3];
        }
        *(f32x4*)(sO + c0) = acc;
    }
    __syncthreads();
    if (tid < 121) {
        float s = 0.f;
#pragma unroll
        for (int hh = 0; hh < 6; hh++) s += sO[hh * 128 + tid];
        s = s * (1.f / 6.f) + b3[tid];
        out[(size_t)d * 121 + tid] = 1.f / (1.f + __expf(-s));
    }
}

// ---------------- launcher ----------------
extern "C" void kernel_launch(void* const* d_in, const int* in_sizes, int n_in,
                              void* d_out, int out_size, void* d_ws, size_t ws_size,
                              hipStream_t stream) {
    const float* x   = (const float*)d_in[0];
    const int*   ei  = (const int*)d_in[1];
    const float* W1  = (const float*)d_in[2];
    const float* as1 = (const float*)d_in[3];
    const float* ad1 = (const float*)d_in[4];
    const float* b1  = (const float*)d_in[5];
    const float* W2  = (const float*)d_in[6];
    const float* as2 = (const float*)d_in[7];
    const float* ad2 = (const float*)d_in[8];
    const float* b2  = (const float*)d_in[9];
    const float* W3  = (const float*)d_in[10];
    const float* as3 = (const float*)d_in[11];
    const float* ad3 = (const float*)d_in[12];
    const float* b3  = (const float*)d_in[13];
    float* out = (float*)d_out;

    float* fws  = (float*)d_ws;
    float* esrc = fws;                      // N*6
    float* edst = fws + 60000;              // N*6
    float* asp  = fws + 120000;             // 768
    float* adp  = fws + 120768;             // 768
    int*   iws  = (int*)(fws + 121536);
    int* deg    = iws;                      // N
    int* rowptr = iws + N_NODES;            // N+1
    int* cursor = iws + 2 * N_NODES + 1;    // N
    int* perm   = iws + 3 * N_NODES + 1;    // E_TOT
    _Float16* f16b = (_Float16*)(fws + 321544);
    _Float16* xh  = f16b;                          // MPAD*1024
    _Float16* xh1 = xh + (size_t)MPAD * 1024;      // MPAD*64
    _Float16* W1h = xh1 + (size_t)MPAD * 64;       // 1024*64
    _Float16* W2h = W1h + 1024 * 64;               // 1024*1024
    _Float16* W3p = W2h + 1024 * 1024;             // 768*1024 (head-padded)
    _Float16* h16 = W3p + 768 * 1024;              // MPAD*1024

    hipMemsetAsync(deg, 0, N_NODES * sizeof(int), stream);
    count_kernel<<<(E_TOT + 255) / 256, 256, 0, stream>>>(ei, deg);
    scan_kernel<<<1, 1024, 0, stream>>>(deg, rowptr, cursor);
    scatter_kernel<<<(E_TOT + 255) / 256, 256, 0, stream>>>(ei, cursor, perm);

    dim3 blk(256);
    cvt_all<<<(CVT_TOTAL + 255) / 256, blk, 0, stream>>>(x, W1, W2, W3, as3, ad3,
                                                          xh1, W1h, W2h, W3p, asp, adp, xh);

    // ---- layer 1: K=50->64, H=4, C=256 ----
    {
        dim3 g(8, 79);
        gemm_mfma<<<g, blk, 0, stream>>>(xh1, W1h, h16, N_NODES, 1024, 64, 1024);
        attn4<<<N_NODES / 4, blk, 0, stream>>>(h16, as1, ad1, esrc, edst);
        agg_big<0><<<N_NODES, blk, 0, stream>>>(h16, esrc, edst, rowptr, perm, b1, xh);
    }
    // ---- layer 2: K=1024, H=4, C=256, residual (read from fp16 xh) ----
    {
        dim3 g(8, 79);
        gemm_mfma<<<g, blk, 0, stream>>>(xh, W2h, h16, N_NODES, 1024, 1024, 1024);
        attn4<<<N_NODES / 4, blk, 0, stream>>>(h16, as2, ad2, esrc, edst);
        agg_big<1><<<N_NODES, blk, 0, stream>>>(h16, esrc, edst, rowptr, perm, b2, xh);
    }
    // ---- layer 3: K=1024, H=6, C=121 (padded 128), mean heads + sigmoid ----
    {
        dim3 g(6, 79);
        gemm_mfma<<<g, blk, 0, stream>>>(xh, W3p, h16, N_NODES, 768, 1024, 768);
        attn6<<<N_NODES / 4, blk, 0, stream>>>(h16, asp, adp, esrc, edst);
        agg_final<<<N_NODES, blk, 0, stream>>>(h16, esrc, edst, rowptr, perm, b3, out);
    }
}